// Round 10
// baseline (431.444 us; speedup 1.0000x reference)
//
#include <hip/hip_runtime.h>

#define BB 512
#define TT 1024
#define II 50
#define HH 32
#define CH 16            // steps per chunk (barrier cadence; = MFMA M)
#define NCH (TT / CH)    // 64 chunks
#define RSLOT 32         // ring slots = 2 chunks (double buffer)

typedef float v2f __attribute__((ext_vector_type(2)));
typedef float v4f __attribute__((ext_vector_type(4)));
typedef short v8s __attribute__((ext_vector_type(8)));        // 8 bf16
typedef _Float16 v2h __attribute__((ext_vector_type(2)));     // half2

__device__ __forceinline__ float fast_rcp(float x) { return __builtin_amdgcn_rcpf(x); }
__device__ __forceinline__ float sigm(float x) { return fast_rcp(1.f + __expf(-x)); }
__device__ __forceinline__ float tanh_(float x) {
    return 1.f - 2.f * fast_rcp(1.f + __expf(2.f * x));   // saturates correctly
}
__device__ __forceinline__ short bf16rne(float f) {      // fp32 -> bf16 RNE
    unsigned u = __float_as_uint(f);
    u += 0x7FFF + ((u >> 16) & 1);
    return (short)(u >> 16);
}
__device__ __forceinline__ v2h asv2h(int v) { return __builtin_bit_cast(v2h, v); }

// d_out is poisoned before every launch: init every element to the combined
// FC bias b_comb = fc3_w @ fc1_b + fc3_b (fc1->fc3 is affine-affine; dropout
// is identity in eval). The scan kernel atomicAdds partial dots on top.
__global__ void init_out_kernel(float* __restrict__ out,
                                const float* __restrict__ fc1_b,
                                const float* __restrict__ fc3_w,
                                const float* __restrict__ fc3_b,
                                int n) {
    int idx = blockIdx.x * blockDim.x + threadIdx.x;
    float b = fc3_b[0];
    #pragma unroll
    for (int k = 0; k < 64; ++k) b += fc3_w[k] * fc1_b[k];
    if (idx < n) out[idx] = b;
}

// One workgroup (128 threads = 2 waves) per BATCH (both directions).
//   wave 0 = CONSUMER: lanes 0-31 fwd seq, lanes 32-63 rev seq; lane owns
//            all 4 gates of one hidden unit (shfl-free chain). hh dot via
//            v_dot2_f32_f16 (2x fp16 MACs, fp32 accumulate, 2x fp32 rate);
//            h stored in LDS as fp16 -> 4x b128 broadcast reads, pairs free.
//   wave 1 = PRODUCER: ih projection for BOTH dirs via bf16 MFMA
//            (32 MFMA / 16-step chunk), plus deferred-FC flush + atomicAdd.
// Ring layout (per step-slot, 256 floats): col = d*128 + cidx(gate);
//   cidx: i_k->2k, f_k->2k+1, g_k->64+2k, o_k->64+2k+1 -> consumer reads two
//   b64s per step, PRELOADED at chunk top (fences trap on-chain otherwise).
// Bias seeded in the consumer's accumulators (MFMA output is biasless).
// MFMA layouts (guide-verified m89/m118/m120):
//   A (16x32): m=lane&15, k=(lane>>4)*8+j ; B (32x16): n=lane&15, same k
//   D (16x16): m=(lane>>4)*4+reg, n=lane&15
// CRITICAL (round-6 lesson): empty asm memory clobber at the end of each
// consumer step pins the hst store->load order across unrolled steps.
__global__ void __launch_bounds__(128, 1) lstm_pc_kernel(
    const float* __restrict__ x,
    const float* __restrict__ w_ih_f, const float* __restrict__ w_hh_f,
    const float* __restrict__ b_ih_f, const float* __restrict__ b_hh_f,
    const float* __restrict__ w_ih_r, const float* __restrict__ w_hh_r,
    const float* __restrict__ b_ih_r, const float* __restrict__ b_hh_r,
    const float* __restrict__ fc1_w, const float* __restrict__ fc3_w,
    float* __restrict__ out)
{
    __shared__ float ringF[RSLOT * 256];        // 32 KB: per-step gate projections
    __shared__ float hbuf[2][HH][65];           // 16.6 KB: deferred FC partials
    __shared__ __align__(16) _Float16 hsth[64]; // 128 B: h(t-1) fp16, both dirs

    const int tid  = threadIdx.x;
    const int lane = tid & 63;
    const int wave = tid >> 6;            // 0 consumer, 1 producer
    const int b    = blockIdx.x;
    float* outb = out + (size_t)b * TT;

    if (wave == 1) {
        // ================= PRODUCER (MFMA ih projection, both dirs) =========
        const float* xb = x + (size_t)b * TT * II;
        const int nl = lane & 15;         // A: m / B: n / D: n
        const int q  = lane >> 4;         // quad 0..3
        const float* wih[2] = {w_ih_f, w_ih_r};

        // B fragments (persistent): Bf[d][nt][kf], n = nt*16+nl, k = kf*32+q*8+j
        v8s Bf[2][8][2];
        #pragma unroll
        for (int d = 0; d < 2; ++d)
            #pragma unroll
            for (int nt = 0; nt < 8; ++nt) {
                const int n = nt * 16 + nl;
                #pragma unroll
                for (int kf = 0; kf < 2; ++kf)
                    #pragma unroll
                    for (int j = 0; j < 8; ++j) {
                        const int k = kf * 32 + q * 8 + j;
                        Bf[d][nt][kf][j] = (k < II) ? bf16rne(wih[d][n * II + k])
                                                    : (short)0;
                    }
            }

        // gate g -> interleaved ring column
        auto cidx = [](int g) -> int {
            return (g < 32) ? 2 * g
                 : (g < 64) ? 2 * (g - 32) + 1
                 : (g < 96) ? 64 + 2 * (g - 64)
                            : 64 + 2 * (g - 96) + 1;
        };

        // produce chunk c for both dirs: fills ring slots c*CH .. c*CH+15
        auto produce_chunk = [&](int c) {
            #pragma unroll
            for (int d = 0; d < 2; ++d) {
                const int S = c * CH + nl;             // this lane's A-row step
                const int t = d ? (TT - 1 - S) : S;
                const float* xr = xb + (size_t)t * II;
                v8s A0, A1;
                #pragma unroll
                for (int j = 0; j < 8; ++j) A0[j] = bf16rne(xr[q * 8 + j]);
                #pragma unroll
                for (int j = 0; j < 8; ++j) {
                    const int k = 32 + q * 8 + j;
                    A1[j] = (k < II) ? bf16rne(xr[k]) : (short)0;
                }
                #pragma unroll
                for (int nt = 0; nt < 8; ++nt) {
                    v4f acc = {0.f, 0.f, 0.f, 0.f};
                    acc = __builtin_amdgcn_mfma_f32_16x16x32_bf16(A0, Bf[d][nt][0], acc, 0, 0, 0);
                    acc = __builtin_amdgcn_mfma_f32_16x16x32_bf16(A1, Bf[d][nt][1], acc, 0, 0, 0);
                    const int col = d * 128 + cidx(nt * 16 + nl);
                    #pragma unroll
                    for (int r = 0; r < 4; ++r) {
                        const int slot = (c * CH + q * 4 + r) & (RSLOT - 1);
                        ringF[slot * 256 + col] = acc[r];
                    }
                }
            }
        };
        // flush chunk m: 16 outputs per dir; lanes 0..31 (d = lane>>4)
        auto flush = [&](int m) {
            if (lane < 32) {
                const int d   = lane >> 4;
                const int idx = lane & 15;
                const int ti  = m * CH + idx;
                const int col = ti & 63;
                float d0 = 0.f, d1 = 0.f, d2 = 0.f, d3 = 0.f;
                #pragma unroll
                for (int k = 0; k < HH; k += 4) {
                    d0 += hbuf[d][k    ][col];
                    d1 += hbuf[d][k + 1][col];
                    d2 += hbuf[d][k + 2][col];
                    d3 += hbuf[d][k + 3][col];
                }
                const int t = d ? (TT - 1 - ti) : ti;
                atomicAdd(&outb[t], (d0 + d1) + (d2 + d3));
            }
        };

        produce_chunk(0);
        __syncthreads();
        for (int n = 0; n < NCH; ++n) {
            if (n + 1 < NCH) produce_chunk(n + 1);
            if (n >= 1) flush(n - 1);
            __syncthreads();
        }
        flush(NCH - 1);
    } else {
        // ================= CONSUMER (recurrence, 2 seqs, fdot2) ============
        const int d = lane >> 5;          // 0 fwd (lanes 0-31), 1 rev
        const int k = lane & 31;          // hidden unit
        const float* w_hh = d ? w_hh_r : w_hh_f;
        const float* bi   = d ? b_ih_r : b_ih_f;
        const float* bh   = d ? b_hh_r : b_hh_f;

        // fp16 K-packed weight pairs for all 4 gate rows of unit k:
        // wph[D][j] = {w_hh[D*32+k][2j], w_hh[D*32+k][2j+1]} (one VGPR each)
        v2h wph[4][16];
        float bb[4];
        #pragma unroll
        for (int D = 0; D < 4; ++D) {
            const int row = D * 32 + k;
            #pragma unroll
            for (int j = 0; j < 16; ++j) {
                wph[D][j].x = (_Float16)w_hh[row * HH + 2 * j];
                wph[D][j].y = (_Float16)w_hh[row * HH + 2 * j + 1];
            }
            bb[D] = bi[row] + bh[row];
        }

        // fused FC weight for hidden unit j = d*32 + k
        float wc = 0.f;
        {
            const int j = d * HH + k;
            #pragma unroll
            for (int n = 0; n < 64; ++n) wc += fc3_w[n] * fc1_w[n * 64 + j];
        }

        hsth[lane] = (_Float16)0.f;       // h(-1) = 0 (same-wave in-order DS)
        float c = 0.f;

        __syncthreads();                  // matches producer's prologue barrier

        for (int n = 0; n < NCH; ++n) {
            const int slot0 = (n & 1) * CH;
            const int col0  = (n & 3) * CH;

            // chunk-top ring preload: all reads issue before any fence
            v2f xz1b[CH], xz2b[CH];
            #pragma unroll
            for (int u = 0; u < CH; ++u) {
                const float* rp = &ringF[(slot0 + u) * 256 + d * 128 + 2 * k];
                xz1b[u] = *(const v2f*)rp;          // {px_i, px_f}
                xz2b[u] = *(const v2f*)(rp + 64);   // {px_g, px_o}
            }

            #pragma unroll
            for (int u = 0; u < CH; ++u) {
                // h(t-1) broadcast: 4x b128 (2 addrs/wave); each 32-bit word
                // is one half2 pair -> pair extraction is free reg select.
                int4 hw0 = *(const int4*)&hsth[d * 32];
                int4 hw1 = *(const int4*)&hsth[d * 32 + 8];
                int4 hw2 = *(const int4*)&hsth[d * 32 + 16];
                int4 hw3 = *(const int4*)&hsth[d * 32 + 24];

                float zA[4], zB[4];
                #pragma unroll
                for (int D = 0; D < 4; ++D) { zA[D] = bb[D]; zB[D] = 0.f; }
                #pragma unroll
                for (int D = 0; D < 4; ++D) {
                    zA[D] = __builtin_amdgcn_fdot2(asv2h(hw0.x), wph[D][0],  zA[D], false);
                    zB[D] = __builtin_amdgcn_fdot2(asv2h(hw0.y), wph[D][1],  zB[D], false);
                    zA[D] = __builtin_amdgcn_fdot2(asv2h(hw0.z), wph[D][2],  zA[D], false);
                    zB[D] = __builtin_amdgcn_fdot2(asv2h(hw0.w), wph[D][3],  zB[D], false);
                    zA[D] = __builtin_amdgcn_fdot2(asv2h(hw1.x), wph[D][4],  zA[D], false);
                    zB[D] = __builtin_amdgcn_fdot2(asv2h(hw1.y), wph[D][5],  zB[D], false);
                    zA[D] = __builtin_amdgcn_fdot2(asv2h(hw1.z), wph[D][6],  zA[D], false);
                    zB[D] = __builtin_amdgcn_fdot2(asv2h(hw1.w), wph[D][7],  zB[D], false);
                    zA[D] = __builtin_amdgcn_fdot2(asv2h(hw2.x), wph[D][8],  zA[D], false);
                    zB[D] = __builtin_amdgcn_fdot2(asv2h(hw2.y), wph[D][9],  zB[D], false);
                    zA[D] = __builtin_amdgcn_fdot2(asv2h(hw2.z), wph[D][10], zA[D], false);
                    zB[D] = __builtin_amdgcn_fdot2(asv2h(hw2.w), wph[D][11], zB[D], false);
                    zA[D] = __builtin_amdgcn_fdot2(asv2h(hw3.x), wph[D][12], zA[D], false);
                    zB[D] = __builtin_amdgcn_fdot2(asv2h(hw3.y), wph[D][13], zB[D], false);
                    zA[D] = __builtin_amdgcn_fdot2(asv2h(hw3.z), wph[D][14], zA[D], false);
                    zB[D] = __builtin_amdgcn_fdot2(asv2h(hw3.w), wph[D][15], zB[D], false);
                }
                const float zi = xz1b[u].x + (zA[0] + zB[0]);
                const float zf = xz1b[u].y + (zA[1] + zB[1]);
                const float zg = xz2b[u].x + (zA[2] + zB[2]);
                const float zo = xz2b[u].y + (zA[3] + zB[3]);

                // all 4 gates in-lane: no cross-lane op on the chain
                const float gi = sigm(zi);
                const float gf = sigm(zf);
                const float gg = tanh_(zg);
                const float go = sigm(zo);

                c = fmaf(gf, c, gi * gg);
                const float h = go * tanh_(c);

                hsth[lane] = (_Float16)h;             // next step's broadcast
                hbuf[d][k][col0 + u] = h * wc;        // deferred FC (fp32)
                // ordering fence: store(u) may not sink, loads(u+1) may not
                // hoist. Zero instructions emitted.
                asm volatile("" ::: "memory");
            }
            __syncthreads();
        }
    }
}

extern "C" void kernel_launch(void* const* d_in, const int* in_sizes, int n_in,
                              void* d_out, int out_size, void* d_ws, size_t ws_size,
                              hipStream_t stream) {
    const float* x      = (const float*)d_in[0];
    const float* w_ih_f = (const float*)d_in[1];
    const float* w_hh_f = (const float*)d_in[2];
    const float* b_ih_f = (const float*)d_in[3];
    const float* b_hh_f = (const float*)d_in[4];
    const float* w_ih_r = (const float*)d_in[5];
    const float* w_hh_r = (const float*)d_in[6];
    const float* b_ih_r = (const float*)d_in[7];
    const float* b_hh_r = (const float*)d_in[8];
    const float* fc1_w  = (const float*)d_in[9];
    const float* fc1_b  = (const float*)d_in[10];
    const float* fc3_w  = (const float*)d_in[11];
    const float* fc3_b  = (const float*)d_in[12];
    float* out = (float*)d_out;

    const int n = BB * TT;
    init_out_kernel<<<(n + 255) / 256, 256, 0, stream>>>(out, fc1_b, fc3_w, fc3_b, n);

    // 512 workgroups = batches; 2 waves each (consumer handles both dirs).
    lstm_pc_kernel<<<BB, 128, 0, stream>>>(
        x, w_ih_f, w_hh_f, b_ih_f, b_hh_f,
        w_ih_r, w_hh_r, b_ih_r, b_hh_r,
        fc1_w, fc3_w, out);
}